// Round 2
// baseline (247.671 us; speedup 1.0000x reference)
//
#include <hip/hip_runtime.h>
#include <float.h>
#include <math.h>
#include <limits.h>

#define NSAMP 100
#define IMG_W 2048
#define IMG_H 2048
#define LANES_PER_PT 4
#define SEG 25   // centers per lane (last lane gets 23)

__device__ __forceinline__ float bilin(const float* __restrict__ img, float x, float y) {
    // x,y already clipped to [0, 2047] -> floor >= 0
    float x0f = floorf(x), y0f = floorf(y);
    float wx = x - x0f, wy = y - y0f;
    int x0 = (int)x0f;
    int y0 = (int)y0f;
    int x1 = min(x0 + 1, IMG_W - 1);
    int y1 = min(y0 + 1, IMG_H - 1);
    float v00 = img[y0 * IMG_W + x0];
    float v01 = img[y0 * IMG_W + x1];
    float v10 = img[y1 * IMG_W + x0];
    float v11 = img[y1 * IMG_W + x1];
    return v00 * (1.f - wx) * (1.f - wy) + v01 * wx * (1.f - wy)
         + v10 * (1.f - wx) * wy       + v11 * wx * wy;
}

__device__ __forceinline__ float tparam(int s) {
    // matches np.linspace(0,1,100) as verified bitwise in round 1
    return (s == NSAMP - 1) ? 1.0f : (float)((double)s * (1.0 / 99.0));
}

__global__ void zero_accum_kernel(double* accum, unsigned int* done) {
    *accum = 0.0;
    *done = 0u;
}

__global__ __launch_bounds__(256) void contour_loss_kernel(
        const float* __restrict__ img,
        const float* __restrict__ points,
        const float* __restrict__ normals,
        double* __restrict__ accum,
        unsigned int* __restrict__ done,
        float* __restrict__ out,
        int N, int nblocks) {
    int t = blockIdx.x * blockDim.x + threadIdx.x;
    int i = t >> 2;        // point index
    int seg = t & 3;       // which quarter of the line this lane covers
    float sq = 0.f;
    if (i < N) {
        float px = fminf(fmaxf(points[2 * i],     0.f), 2047.f);
        float py = fminf(fmaxf(points[2 * i + 1], 0.f), 2047.f);
        float nx = normals[2 * i];
        float ny = normals[2 * i + 1];
        // d = normalize([-ny, nx])
        float ddx = -ny, ddy = nx;
        float nrm = sqrtf(ddx * ddx + ddy * ddy);
        float dx = ddx / nrm, dy = ddy / nrm;

        const float maxf = FLT_MAX;
        float sdx = (dx != 0.f) ? dx : 1.f;
        float sdy = (dy != 0.f) ? dy : 1.f;
        float t_left   = (dx != 0.f) ? (0.f    - px) / sdx : -maxf;
        float t_right  = (dx != 0.f) ? (2047.f - px) / sdx :  maxf;
        float t_top    = (dy != 0.f) ? (0.f    - py) / sdy : -maxf;
        float t_bottom = (dy != 0.f) ? (2047.f - py) / sdy :  maxf;
        float t_min = fmaxf(t_left, t_top);
        float t_max = fminf(t_right, t_bottom);

        float p1x = px + t_min * dx, p1y = py + t_min * dy;
        float p2x = px + t_max * dx, p2y = py + t_max * dy;
        float vx = p2x - p1x, vy = p2y - p1y;

        // ref_val: only needed by seg 0 (reduces divergent gathers)
        float ref_val = 0.f;
        if (seg == 0) ref_val = bilin(img, px, py);

        // this lane's sample range: [s_begin, s_end] inclusive; centers s_begin+1 .. s_end-1
        int s_begin = SEG * seg;
        int s_end   = min(s_begin + SEG + 1, NSAMP - 1);

        // preload first two samples of the window
        float tt = tparam(s_begin);
        float lx = fminf(fmaxf(p1x + tt * vx, 0.f), 2047.f);
        float ly = fminf(fmaxf(p1y + tt * vy, 0.f), 2047.f);
        float v_im1 = bilin(img, lx, ly);
        tt = tparam(s_begin + 1);
        lx = fminf(fmaxf(p1x + tt * vx, 0.f), 2047.f);
        ly = fminf(fmaxf(p1y + tt * vy, 0.f), 2047.f);
        float v_i = bilin(img, lx, ly);
        float cx = lx, cy = ly;

        float best_d2  = INFINITY;
        int   best_idx = INT_MAX;
        float best_val = 0.f;
        if (seg == 0) {      // default candidate: argmin(all-inf)==0 -> vals[1]
            best_idx = 0;
            best_val = v_i;  // v at global sample index 1
        }

        #pragma unroll 4
        for (int s = s_begin + 2; s <= s_end; ++s) {
            float ts = tparam(s);
            float nlx = fminf(fmaxf(p1x + ts * vx, 0.f), 2047.f);
            float nly = fminf(fmaxf(p1y + ts * vy, 0.f), 2047.f);
            float v_ip1 = bilin(img, nlx, nly);
            // center sample index = s-1
            if (v_i < v_im1 && v_i < v_ip1) {
                float ex = cx - px, ey = cy - py;
                float d2 = ex * ex + ey * ey;
                if (d2 < best_d2) { best_d2 = d2; best_idx = s - 1; best_val = v_i; }
            }
            v_im1 = v_i; v_i = v_ip1; cx = nlx; cy = nly;
        }

        // reduce candidates across the 4 lanes of this point (lanes t..t+3 in-wave)
        #pragma unroll
        for (int m = 1; m <= 2; m <<= 1) {
            float od2  = __shfl_xor(best_d2, m);
            int   oidx = __shfl_xor(best_idx, m);
            float oval = __shfl_xor(best_val, m);
            if (od2 < best_d2 || (od2 == best_d2 && oidx < best_idx)) {
                best_d2 = od2; best_idx = oidx; best_val = oval;
            }
        }

        if (seg == 0) {
            float diff = best_val - ref_val;
            sq = diff * diff;
        }
    }

    // wave (64-lane) shuffle reduction
    for (int off = 32; off > 0; off >>= 1)
        sq += __shfl_down(sq, off);
    __shared__ float wsum[4];
    int lane = threadIdx.x & 63;
    int wid  = threadIdx.x >> 6;
    if (lane == 0) wsum[wid] = sq;
    __syncthreads();
    if (threadIdx.x == 0) {
        float bs = wsum[0] + wsum[1] + wsum[2] + wsum[3];
        atomicAdd(accum, (double)bs);
        __threadfence();
        unsigned int prev = atomicAdd(done, 1u);
        if (prev == (unsigned int)(nblocks - 1)) {
            double total = atomicAdd(accum, 0.0);  // coherent read of final sum
            out[0] = (float)(total / (double)N);
        }
    }
}

extern "C" void kernel_launch(void* const* d_in, const int* in_sizes, int n_in,
                              void* d_out, int out_size, void* d_ws, size_t ws_size,
                              hipStream_t stream) {
    const float* img     = (const float*)d_in[0];
    const float* points  = (const float*)d_in[1];
    const float* normals = (const float*)d_in[2];
    int N = in_sizes[1] / 2;
    float* out = (float*)d_out;
    double* accum = (double*)d_ws;
    unsigned int* done = (unsigned int*)((char*)d_ws + sizeof(double));

    zero_accum_kernel<<<1, 1, 0, stream>>>(accum, done);
    int block = 256;
    int threads_needed = N * LANES_PER_PT;
    int grid = (threads_needed + block - 1) / block;
    contour_loss_kernel<<<grid, block, 0, stream>>>(img, points, normals,
                                                    accum, done, out, N, grid);
}

// Round 3
// 149.027 us; speedup vs baseline: 1.6619x; 1.6619x over previous
//
#include <hip/hip_runtime.h>
#include <float.h>
#include <math.h>

#define NSAMP 100
#define IMG_W 2048
#define IMG_H 2048

typedef _Float16 h2_t __attribute__((ext_vector_type(2), aligned(2)));
typedef _Float16 h8_t __attribute__((ext_vector_type(8), aligned(16)));

__global__ void zero_accum_kernel(double* accum, unsigned int* done) {
    *accum = 0.0;
    *done = 0u;
}

// fp32 -> fp16 image conversion: 8 floats per thread
__global__ __launch_bounds__(256) void convert_kernel(const float* __restrict__ in,
                                                      _Float16* __restrict__ out) {
    int idx = blockIdx.x * blockDim.x + threadIdx.x;
    const float4* in4 = (const float4*)in;
    float4 a = in4[2 * idx];
    float4 b = in4[2 * idx + 1];
    h8_t o;
    o[0] = (_Float16)a.x; o[1] = (_Float16)a.y; o[2] = (_Float16)a.z; o[3] = (_Float16)a.w;
    o[4] = (_Float16)b.x; o[5] = (_Float16)b.y; o[6] = (_Float16)b.z; o[7] = (_Float16)b.w;
    *(h8_t*)(out + 8 * idx) = o;
}

__device__ __forceinline__ float bilin16(const _Float16* __restrict__ img, float x, float y) {
    // x,y already clipped to [0, 2047]
    float x0f = floorf(x), y0f = floorf(y);
    float wx = x - x0f, wy = y - y0f;
    int x0 = (int)x0f;
    int y0 = (int)y0f;
    int y1 = min(y0 + 1, IMG_H - 1);
    int xa = min(x0, IMG_W - 2);          // pair base; if x0==2047 shift left one
    bool edge = (x0 == IMG_W - 1);        // then wx==0, v01 weight is exactly 0
    h2_t p0 = *(const h2_t*)(img + y0 * IMG_W + xa);
    h2_t p1 = *(const h2_t*)(img + y1 * IMG_W + xa);
    float v00 = edge ? (float)p0[1] : (float)p0[0];
    float v01 = (float)p0[1];
    float v10 = edge ? (float)p1[1] : (float)p1[0];
    float v11 = (float)p1[1];
    return v00 * (1.f - wx) * (1.f - wy) + v01 * wx * (1.f - wy)
         + v10 * (1.f - wx) * wy       + v11 * wx * wy;
}

__device__ __forceinline__ float tparam(int s) {
    return (s == NSAMP - 1) ? 1.0f : (float)((double)s * (1.0 / 99.0));
}

__global__ __launch_bounds__(256) void contour_loss_kernel(
        const _Float16* __restrict__ img,
        const float* __restrict__ points,
        const float* __restrict__ normals,
        double* __restrict__ accum,
        unsigned int* __restrict__ done,
        float* __restrict__ out,
        int N, int nblocks) {
    int i = blockIdx.x * blockDim.x + threadIdx.x;
    float sq = 0.f;
    if (i < N) {
        float px = fminf(fmaxf(points[2 * i],     0.f), 2047.f);
        float py = fminf(fmaxf(points[2 * i + 1], 0.f), 2047.f);
        float nx = normals[2 * i];
        float ny = normals[2 * i + 1];
        float ddx = -ny, ddy = nx;
        float nrm = sqrtf(ddx * ddx + ddy * ddy);
        float dx = ddx / nrm, dy = ddy / nrm;

        const float maxf = FLT_MAX;
        float sdx = (dx != 0.f) ? dx : 1.f;
        float sdy = (dy != 0.f) ? dy : 1.f;
        float t_left   = (dx != 0.f) ? (0.f    - px) / sdx : -maxf;
        float t_right  = (dx != 0.f) ? (2047.f - px) / sdx :  maxf;
        float t_top    = (dy != 0.f) ? (0.f    - py) / sdy : -maxf;
        float t_bottom = (dy != 0.f) ? (2047.f - py) / sdy :  maxf;
        float t_min = fmaxf(t_left, t_top);
        float t_max = fminf(t_right, t_bottom);

        float p1x = px + t_min * dx, p1y = py + t_min * dy;
        float p2x = px + t_max * dx, p2y = py + t_max * dy;
        float vx = p2x - p1x, vy = p2y - p1y;

        float ref_val = bilin16(img, px, py);

        // sample s=0
        float lx = fminf(fmaxf(p1x, 0.f), 2047.f);
        float ly = fminf(fmaxf(p1y, 0.f), 2047.f);
        float v_im1 = bilin16(img, lx, ly);
        // sample s=1
        float t1 = tparam(1);
        lx = fminf(fmaxf(p1x + t1 * vx, 0.f), 2047.f);
        ly = fminf(fmaxf(p1y + t1 * vy, 0.f), 2047.f);
        float v_i = bilin16(img, lx, ly);
        float cx = lx, cy = ly;

        float best_val = v_i;     // argmin(all-inf)==0 -> vals[1]
        float best_d2  = INFINITY;

        #pragma unroll 4
        for (int s = 2; s < NSAMP; ++s) {
            float ts = tparam(s);
            float nlx = fminf(fmaxf(p1x + ts * vx, 0.f), 2047.f);
            float nly = fminf(fmaxf(p1y + ts * vy, 0.f), 2047.f);
            float v_ip1 = bilin16(img, nlx, nly);
            if (v_i < v_im1 && v_i < v_ip1) {
                float ex = cx - px, ey = cy - py;
                float d2 = ex * ex + ey * ey;
                if (d2 < best_d2) { best_d2 = d2; best_val = v_i; }
            }
            v_im1 = v_i; v_i = v_ip1; cx = nlx; cy = nly;
        }
        float diff = best_val - ref_val;
        sq = diff * diff;
    }

    // wave (64-lane) shuffle reduction
    for (int off = 32; off > 0; off >>= 1)
        sq += __shfl_down(sq, off);
    __shared__ float wsum[4];
    int lane = threadIdx.x & 63;
    int wid  = threadIdx.x >> 6;
    if (lane == 0) wsum[wid] = sq;
    __syncthreads();
    if (threadIdx.x == 0) {
        float bs = wsum[0] + wsum[1] + wsum[2] + wsum[3];
        atomicAdd(accum, (double)bs);
        __threadfence();
        unsigned int prev = atomicAdd(done, 1u);
        if (prev == (unsigned int)(nblocks - 1)) {
            double total = atomicAdd(accum, 0.0);  // device-scope coherent read
            out[0] = (float)(total / (double)N);
        }
    }
}

extern "C" void kernel_launch(void* const* d_in, const int* in_sizes, int n_in,
                              void* d_out, int out_size, void* d_ws, size_t ws_size,
                              hipStream_t stream) {
    const float* img     = (const float*)d_in[0];
    const float* points  = (const float*)d_in[1];
    const float* normals = (const float*)d_in[2];
    int N = in_sizes[1] / 2;
    float* out = (float*)d_out;

    // d_ws layout: [0, 8 MiB) fp16 image; then accum (double); then done (uint)
    _Float16* img16 = (_Float16*)d_ws;
    double* accum = (double*)((char*)d_ws + (size_t)IMG_W * IMG_H * sizeof(_Float16));
    unsigned int* done = (unsigned int*)(accum + 1);

    zero_accum_kernel<<<1, 1, 0, stream>>>(accum, done);

    int conv_threads = (IMG_W * IMG_H) / 8;           // 8 floats per thread
    convert_kernel<<<conv_threads / 256, 256, 0, stream>>>(img, img16);

    int block = 256;
    int grid = (N + block - 1) / block;
    contour_loss_kernel<<<grid, block, 0, stream>>>(img16, points, normals,
                                                    accum, done, out, N, grid);
}